// Round 2
// baseline (341.316 us; speedup 1.0000x reference)
//
#include <hip/hip_runtime.h>

// MultiHeadEMA, single-kernel 3-phase with software grid barrier.
//   out[b,l,d] = omega[d]*x[b,l,d] + sum_n gc[d,n] * u_n[b,l,d]
//   u_n[l] = q_n * u_n[l-1] + x[l],  u_n[-1] = 0
//   q_n  = 1 - sigmoid(delta)*sigmoid(alpha)
//   gc_n = sigmoid(delta)*beta * gamma * sqrt(1/N)
//
// Phase 1: each block computes NTASK chunk-local scans, publishes end states E
//          via sc0/sc1 WRITE-THROUGH stores (coherence point, never dirty-L2).
// Barrier. Phase 2: one thread per (b,n,d) scans chunk states across g
//          (S[g] = E[g] + q^C * S[g-1]) with sc0/sc1 loads+stores, UF-batched.
// Barrier. Phase 3: rescan each chunk seeded with S[g-1] (sc0/sc1 loads),
//          fused residual, plain out stores.
//
// Grid barrier: 512 blocks = 2 blocks/CU on 256 CUs under
// __launch_bounds__(256,2) -> whole grid co-resident, no block retires before
// the barrier -> deadlock-free. Arrival via atomicAdd (device-scope, m20);
// spin reads via sc0/sc1 bypass loads. All cross-block payloads go through
// the coherence point, so per-XCD L2 non-coherence cannot produce staleness
// (root cause of the round-1 failure).

#define BB 8
#define LL 4096
#define DD 1024
#define NN 16
#define UF 8
#define NB 512          // grid blocks; 2/CU -- residency-safe for the barrier

__device__ __forceinline__ float sigmoid_precise(float v) {
    return 1.0f / (1.0f + expf(-v));
}

// ---- coherent (sc0 sc1) asm memory ops: bypass non-coherent per-XCD L2 ----
__device__ __forceinline__ void sc_store(float* p, float v) {
    asm volatile("global_store_dword %0, %1, off sc0 sc1"
                 :: "v"(p), "v"(v) : "memory");
}
__device__ __forceinline__ int sc_load_i(const int* p) {
    int v;
    asm volatile("global_load_dword %0, %1, off sc0 sc1\n\t"
                 "s_waitcnt vmcnt(0)"
                 : "=v"(v) : "v"(p) : "memory");
    return v;
}
__device__ __forceinline__ void sc_load4(const float* p0, const float* p1,
                                         const float* p2, const float* p3,
                                         float& o0, float& o1, float& o2, float& o3) {
    asm volatile(
        "global_load_dword %0, %4, off sc0 sc1\n\t"
        "global_load_dword %1, %5, off sc0 sc1\n\t"
        "global_load_dword %2, %6, off sc0 sc1\n\t"
        "global_load_dword %3, %7, off sc0 sc1\n\t"
        "s_waitcnt vmcnt(0)"
        : "=&v"(o0), "=&v"(o1), "=&v"(o2), "=&v"(o3)
        : "v"(p0), "v"(p1), "v"(p2), "v"(p3)
        : "memory");
}
__device__ __forceinline__ void sc_load8s(const float* p, size_t stride, float* o) {
    const float* a0 = p;
    const float* a1 = p + stride;
    const float* a2 = p + 2 * stride;
    const float* a3 = p + 3 * stride;
    const float* a4 = p + 4 * stride;
    const float* a5 = p + 5 * stride;
    const float* a6 = p + 6 * stride;
    const float* a7 = p + 7 * stride;
    asm volatile(
        "global_load_dword %0, %8, off sc0 sc1\n\t"
        "global_load_dword %1, %9, off sc0 sc1\n\t"
        "global_load_dword %2, %10, off sc0 sc1\n\t"
        "global_load_dword %3, %11, off sc0 sc1\n\t"
        "global_load_dword %4, %12, off sc0 sc1\n\t"
        "global_load_dword %5, %13, off sc0 sc1\n\t"
        "global_load_dword %6, %14, off sc0 sc1\n\t"
        "global_load_dword %7, %15, off sc0 sc1\n\t"
        "s_waitcnt vmcnt(0)"
        : "=&v"(o[0]), "=&v"(o[1]), "=&v"(o[2]), "=&v"(o[3]),
          "=&v"(o[4]), "=&v"(o[5]), "=&v"(o[6]), "=&v"(o[7])
        : "v"(a0), "v"(a1), "v"(a2), "v"(a3),
          "v"(a4), "v"(a5), "v"(a6), "v"(a7)
        : "memory");
}
__device__ __forceinline__ void vm_drain() {
    asm volatile("s_waitcnt vmcnt(0)" ::: "memory");
}

// Software grid barrier. Every wave drains its own VMEM (sc stores ack at the
// coherence point), block-barrier, one arrival atomic, spin on bypass loads.
__device__ __forceinline__ void grid_barrier(int* bar) {
    vm_drain();
    __syncthreads();
    if (threadIdx.x == 0) {
        atomicAdd(bar, 1);                       // device-scope (m20)
        while (sc_load_i(bar) < NB)
            __builtin_amdgcn_s_sleep(2);
    }
    __syncthreads();
}

template <int G_>
__global__ __launch_bounds__(256, 2) void ema_onepass(
    const float* __restrict__ x,
    const float* __restrict__ delta,
    const float* __restrict__ alpha,
    const float* __restrict__ beta,
    const float* __restrict__ gamma,
    const float* __restrict__ omega,
    float* __restrict__ out,
    float* __restrict__ E,        // [BB][G_][NN][DD], scanned in place
    int*   __restrict__ bar)      // [2] grid-barrier counters (memset到0)
{
    constexpr int C_    = LL / G_;
    constexpr int NTASK = (32 * G_) / NB;     // 4 for G=64, 2 for G=32
    static_assert((C_ & (C_ - 1)) == 0, "C_ must be a power of two");
    static_assert(32 * G_ == NB * NTASK, "task tiling must be exact");

    const int blk   = blockIdx.x;
    const int chain = blk & 31;               // (b, dblk): same for all tasks
    const int b     = chain >> 2;
    const int dblk  = chain & 3;
    const int d     = dblk * 256 + threadIdx.x;

    float q[NN], gc[NN];
#pragma unroll
    for (int n = 0; n < NN; ++n) {
        const float p = sigmoid_precise(delta[d * NN + n]);
        const float a = sigmoid_precise(alpha[d * NN + n]);
        q[n]  = 1.0f - p * a;
        gc[n] = p * beta[d * NN + n] * gamma[d * NN + n] * 0.25f; // sqrt(1/16)
    }
    const float om = omega[d];

    // ---- phase 1: local scans; publish chunk end states E (write-through) ----
    for (int k = 0; k < NTASK; ++k) {
        const int g = (blk >> 5) + k * (G_ / NTASK);
        const float* xp = x + ((size_t)b * LL + (size_t)g * C_) * DD + d;

        float u[NN];
#pragma unroll
        for (int n = 0; n < NN; ++n) u[n] = 0.0f;
        for (int ii = 0; ii < C_; ii += UF) {
            float xv[UF];
#pragma unroll
            for (int j = 0; j < UF; ++j)
                xv[j] = xp[(size_t)(ii + j) * DD];
#pragma unroll
            for (int j = 0; j < UF; ++j)
#pragma unroll
                for (int n = 0; n < NN; ++n)
                    u[n] = fmaf(q[n], u[n], xv[j]);
        }
        float* Ep = E + (((size_t)b * G_ + g) * NN) * DD + d;
#pragma unroll
        for (int n = 0; n < NN; ++n)
            sc_store(Ep + (size_t)n * DD, u[n]);
    }

    grid_barrier(&bar[0]);

    // ---- phase 2: carry scan across g, one thread per (b,n,d) ----
    {
        const int tt = blk * 256 + threadIdx.x;       // 0..131071 == BB*NN*DD
        const int sd = tt & (DD - 1);
        const int sn = (tt >> 10) & (NN - 1);
        const int sb = tt >> 14;

        const float sp = sigmoid_precise(delta[sd * NN + sn]);
        const float sa = sigmoid_precise(alpha[sd * NN + sn]);
        const float sq = 1.0f - sp * sa;
        float Qc = sq;                                // q^C by repeated squaring
#pragma unroll
        for (int s2 = 1; s2 < C_; s2 <<= 1) Qc *= Qc;

        float* Ep = E + ((size_t)sb * G_ * NN + sn) * DD + sd;
        const size_t gs = (size_t)NN * DD;

        float u = 0.0f;
        for (int gg = 0; gg < G_; gg += UF) {
            float ev[UF];
            sc_load8s(Ep + (size_t)gg * gs, gs, ev);
            float sv[UF];
#pragma unroll
            for (int j = 0; j < UF; ++j) {
                u = fmaf(Qc, u, ev[j]);
                sv[j] = u;
            }
#pragma unroll
            for (int j = 0; j < UF; ++j)
                sc_store(Ep + (size_t)(gg + j) * gs, sv[j]);
        }
    }

    grid_barrier(&bar[1]);

    // ---- phase 3: rescan seeded with S[g-1]; fused residual; write out ----
    for (int k = 0; k < NTASK; ++k) {
        const int g = (blk >> 5) + k * (G_ / NTASK);
        const float* xp = x + ((size_t)b * LL + (size_t)g * C_) * DD + d;
        float*       op = out + ((size_t)b * LL + (size_t)g * C_) * DD + d;

        float u[NN];
        if (g > 0) {
            const float* Sp = E + (((size_t)b * G_ + (g - 1)) * NN) * DD + d;
#pragma unroll
            for (int n = 0; n < NN; n += 4)
                sc_load4(Sp + (size_t)(n + 0) * DD, Sp + (size_t)(n + 1) * DD,
                         Sp + (size_t)(n + 2) * DD, Sp + (size_t)(n + 3) * DD,
                         u[n + 0], u[n + 1], u[n + 2], u[n + 3]);
        } else {
#pragma unroll
            for (int n = 0; n < NN; ++n) u[n] = 0.0f;
        }

        for (int ii = 0; ii < C_; ii += UF) {
            float xv[UF];
#pragma unroll
            for (int j = 0; j < UF; ++j)
                xv[j] = xp[(size_t)(ii + j) * DD];
#pragma unroll
            for (int j = 0; j < UF; ++j) {
                const float xvj = xv[j];
                float a0 = om * xvj, a1 = 0.0f, a2 = 0.0f, a3 = 0.0f;
#pragma unroll
                for (int n = 0; n < NN; n += 4) {
                    u[n + 0] = fmaf(q[n + 0], u[n + 0], xvj);
                    u[n + 1] = fmaf(q[n + 1], u[n + 1], xvj);
                    u[n + 2] = fmaf(q[n + 2], u[n + 2], xvj);
                    u[n + 3] = fmaf(q[n + 3], u[n + 3], xvj);
                    a0 = fmaf(gc[n + 0], u[n + 0], a0);
                    a1 = fmaf(gc[n + 1], u[n + 1], a1);
                    a2 = fmaf(gc[n + 2], u[n + 2], a2);
                    a3 = fmaf(gc[n + 3], u[n + 3], a3);
                }
                op[(size_t)(ii + j) * DD] = (a0 + a1) + (a2 + a3);
            }
        }
    }
}

extern "C" void kernel_launch(void* const* d_in, const int* in_sizes, int n_in,
                              void* d_out, int out_size, void* d_ws, size_t ws_size,
                              hipStream_t stream) {
    const float* x     = (const float*)d_in[0];
    const float* delta = (const float*)d_in[1];
    const float* alpha = (const float*)d_in[2];
    const float* beta  = (const float*)d_in[3];
    const float* gamma = (const float*)d_in[4];
    const float* omega = (const float*)d_in[5];
    float* out = (float*)d_out;

    int*   bar = (int*)d_ws;
    float* E   = (float*)((char*)d_ws + 256);

    hipMemsetAsync(d_ws, 0, 256, stream);   // reset barrier counters

    const size_t need64 = 256 + (size_t)BB * 64 * NN * DD * sizeof(float);
    if (ws_size >= need64)
        hipLaunchKernelGGL(ema_onepass<64>, dim3(NB), dim3(256), 0, stream,
                           x, delta, alpha, beta, gamma, omega, out, E, bar);
    else
        hipLaunchKernelGGL(ema_onepass<32>, dim3(NB), dim3(256), 0, stream,
                           x, delta, alpha, beta, gamma, omega, out, E, bar);
}